// Round 1
// baseline (2827.401 us; speedup 1.0000x reference)
//
#include <hip/hip_runtime.h>

#define T_STEPS 65536
#define D_TAPS  20
#define NZ      512
#define TT      32

// persistent device scratch (avoids d_ws size uncertainty; fully rewritten every call)
__device__ float g_M[NZ * NZ];              // 512x512 combined transition matrix
__device__ float g_G[D_TAPS * NZ * 32];     // G[d][i][c] = (M^d B)[i][c]
__device__ float g_Zeta[D_TAPS * NZ];       // Zeta[d][i] = (M^d z0)[i]
__device__ float g_BH[2][33 * NZ];          // ping-pong chain state, layout [c][j]

// ---------------------------------------------------------------------------
// Kernel 1: build M, and init BH_0 = [B | z0], G[0] = B, Zeta[0] = z0
// grid: 1024 x 256  (one thread per M entry)
// ---------------------------------------------------------------------------
__global__ __launch_bounds__(256) void k_build(
    const float* __restrict__ xn0, const float* __restrict__ xu0, const float* __restrict__ xo0,
    const float* __restrict__ Ann, const float* __restrict__ Kn,  const float* __restrict__ Cn,
    const float* __restrict__ Auu, const float* __restrict__ Ku,  const float* __restrict__ Cu,
    const float* __restrict__ Bpn, const float* __restrict__ Bpu,
    const float* __restrict__ Ao,  const float* __restrict__ Bo,  const float* __restrict__ Co)
{
    int q = blockIdx.x * 256 + threadIdx.x;   // 0 .. 262143
    int i = q >> 9, j = q & 511;
    float v;
    if (i < 128) {                                     // nat rows
        if (j < 128)       v = Ann[i * 128 + j] + Kn[i] * Cn[j];
        else if (j < 256)  v = Kn[i] * Cu[j - 128];
        else {
            int jp = j - 256; float s = 0.f;
            #pragma unroll 8
            for (int c = 0; c < 64; c++) s += Bpn[i * 64 + c] * Co[c * 256 + jp];
            v = s;
        }
    } else if (i < 256) {                              // unnat rows (x_nat dep cancels exactly)
        int ip = i - 128;
        if (j < 128)       v = 0.f;
        else if (j < 256)  { int jp = j - 128; v = Auu[ip * 128 + jp] + Ku[ip] * Cu[jp]; }
        else {
            int jp = j - 256; float s = 0.f;
            #pragma unroll 8
            for (int c = 0; c < 64; c++) s += Bpu[ip * 64 + c] * Co[c * 256 + jp];
            v = s;
        }
    } else {                                           // opsin rows
        int ip = i - 256;
        v = (j >= 256) ? Ao[ip * 256 + (j - 256)] : 0.f;
    }
    g_M[q] = v;

    if (q < 33 * NZ) {
        int jj = q & 511, cc = q >> 9;                 // cc in 0..32
        if (cc < 32) {
            float b = (jj >= 256) ? Bo[(jj - 256) * 32 + cc] : 0.f;
            g_BH[0][cc * NZ + jj] = b;
            g_G[jj * 32 + cc]     = b;                 // G[0] = B
        } else {
            float z0j = (jj < 128) ? xn0[jj] : (jj < 256 ? xu0[jj - 128] : xo0[jj - 256]);
            g_BH[0][32 * NZ + jj] = z0j;
            g_Zeta[jj]            = z0j;               // Zeta[0] = z0
        }
    }
}

// ---------------------------------------------------------------------------
// Kernel 2: one chain step  BH_{d+1} = M * BH_d ; scatter into G[d+1], Zeta[d+1]
// grid: 66 x 256  (one thread per output element, 33*512)
// ---------------------------------------------------------------------------
__global__ __launch_bounds__(256) void k_chain(int d)
{
    int q = blockIdx.x * 256 + threadIdx.x;   // 0 .. 16895
    int i = q & 511, c = q >> 9;              // c in 0..32
    const float4* Mrow = (const float4*)(g_M + (size_t)i * NZ);
    const float4* srow = (const float4*)(g_BH[d & 1] + (size_t)c * NZ);
    float s = 0.f;
    #pragma unroll 8
    for (int k = 0; k < 128; k++) {
        float4 m = Mrow[k], x = srow[k];
        s += m.x * x.x + m.y * x.y + m.z * x.z + m.w * x.w;
    }
    g_BH[(d & 1) ^ 1][c * NZ + i] = s;
    if (c < 32) g_G[(size_t)(d + 1) * NZ * 32 + i * 32 + c] = s;
    else        g_Zeta[(d + 1) * NZ + i] = s;
}

// ---------------------------------------------------------------------------
// Kernel 3: FIR evaluation of all states + y, + output scatter
// block: 256 threads = 512 dims (2 per thread) x TT=32 time steps
// grid: ceil((T+1)/TT) = 2049 blocks
// ---------------------------------------------------------------------------
__global__ __launch_bounds__(256) void k_fir(
    const float* __restrict__ U, const float* __restrict__ Cn, const float* __restrict__ Cu,
    float* __restrict__ out)
{
    const int tid = threadIdx.x;
    const int t0  = blockIdx.x * TT;

    __shared__ float u_lds[(TT + D_TAPS) * 32];   // 52 rows, rows 0..50 used
    __shared__ float ypart[4][TT];

    // stage u rows [t0-20, t0+30], zero-padded outside [0, T) -> makes tap
    // clipping at t<D and the tail tile automatic (taps on padded rows add 0)
    for (int e = tid; e < 51 * 32; e += 256) {
        int row = e >> 5, c = e & 31;
        int gr = t0 - D_TAPS + row;
        u_lds[e] = (gr >= 0 && gr < T_STEPS) ? U[gr * 32 + c] : 0.f;
    }
    __syncthreads();

    const int i0 = tid;          // dim 0..255   (nat + unnat)
    const int i1 = tid + 256;    // dim 256..511 (opsin)
    float acc0[TT], acc1[TT];
    #pragma unroll
    for (int t = 0; t < TT; t++) { acc0[t] = 0.f; acc1[t] = 0.f; }

    for (int d = 0; d < D_TAPS; d++) {
        const float4* g0 = (const float4*)(g_G + ((size_t)d * NZ + i0) * 32);
        const float4* g1 = (const float4*)(g_G + ((size_t)d * NZ + i1) * 32);
        #pragma unroll
        for (int cb = 0; cb < 2; cb++) {
            float4 h0[4], h1[4];
            #pragma unroll
            for (int k = 0; k < 4; k++) { h0[k] = g0[cb * 4 + k]; h1[k] = g1[cb * 4 + k]; }
            #pragma unroll
            for (int t = 0; t < TT; t++) {
                const float4* ur = (const float4*)&u_lds[(t + (D_TAPS - 1) - d) * 32 + cb * 16];
                float s0 = 0.f, s1 = 0.f;
                #pragma unroll
                for (int k = 0; k < 4; k++) {
                    float4 u4 = ur[k];
                    s0 += h0[k].x * u4.x + h0[k].y * u4.y + h0[k].z * u4.z + h0[k].w * u4.w;
                    s1 += h1[k].x * u4.x + h1[k].y * u4.y + h1[k].z * u4.z + h1[k].w * u4.w;
                }
                acc0[t] += s0; acc1[t] += s1;
            }
        }
    }

    const float cyv = (i0 < 128) ? Cn[i0] : Cu[i0 - 128];
    const int wid = tid >> 6, lane = tid & 63;

    const size_t O1 = (size_t)T_STEPS;                        // x_nat_hist
    const size_t O2 = O1 + (size_t)(T_STEPS + 1) * 128;       // x_unnat_hist
    const size_t O3 = O2 + (size_t)(T_STEPS + 1) * 128;       // x_opsin_hist

    #pragma unroll
    for (int t = 0; t < TT; t++) {
        int gt = t0 + t;
        if (gt > T_STEPS) break;          // uniform across block
        float z0v = acc0[t], z1v = acc1[t];
        if (gt < D_TAPS) {                // exact initial-condition term, t < 20
            z0v += g_Zeta[gt * NZ + i0];
            z1v += g_Zeta[gt * NZ + i1];
        }
        if (i0 < 128) out[O1 + (size_t)gt * 128 + i0]         = z0v;
        else          out[O2 + (size_t)gt * 128 + (i0 - 128)] = z0v;
        out[O3 + (size_t)gt * 256 + (i1 - 256)] = z1v;

        // y_t = cy . z_t  (pre-update state), reduce over the 256 nat/unnat dims
        float yv = cyv * z0v;
        #pragma unroll
        for (int off = 32; off >= 1; off >>= 1) yv += __shfl_xor(yv, off, 64);
        if (lane == 0) ypart[wid][t] = yv;
    }
    __syncthreads();
    if (tid < TT) {
        int gt = t0 + tid;
        if (gt < T_STEPS)
            out[gt] = ypart[0][tid] + ypart[1][tid] + ypart[2][tid] + ypart[3][tid];
    }
}

extern "C" void kernel_launch(void* const* d_in, const int* in_sizes, int n_in,
                              void* d_out, int out_size, void* d_ws, size_t ws_size,
                              hipStream_t stream)
{
    const float* xn0 = (const float*)d_in[0];
    const float* xu0 = (const float*)d_in[1];
    const float* xo0 = (const float*)d_in[2];
    const float* U   = (const float*)d_in[3];
    const float* Ann = (const float*)d_in[4];
    const float* Kn  = (const float*)d_in[5];
    const float* Cn  = (const float*)d_in[6];
    const float* Auu = (const float*)d_in[7];
    const float* Ku  = (const float*)d_in[8];
    const float* Cu  = (const float*)d_in[9];
    const float* Bpn = (const float*)d_in[10];
    const float* Bpu = (const float*)d_in[11];
    const float* Ao  = (const float*)d_in[12];
    const float* Bo  = (const float*)d_in[13];
    const float* Co  = (const float*)d_in[14];
    float* out = (float*)d_out;

    k_build<<<dim3(1024), dim3(256), 0, stream>>>(xn0, xu0, xo0, Ann, Kn, Cn,
                                                  Auu, Ku, Cu, Bpn, Bpu, Ao, Bo, Co);
    for (int d = 0; d < D_TAPS - 1; d++)
        k_chain<<<dim3(66), dim3(256), 0, stream>>>(d);

    k_fir<<<dim3((T_STEPS + 1 + TT - 1) / TT), dim3(256), 0, stream>>>(U, Cn, Cu, out);
}

// Round 2
// 793.896 us; speedup vs baseline: 3.5614x; 3.5614x over previous
//
#include <hip/hip_runtime.h>

#define T_STEPS 65536
#define D_TAPS  12
#define NZ      512
#define KTOT    (D_TAPS * 32)

// persistent device scratch (fully rewritten every call)
__device__ float g_M[NZ * NZ];             // 512x512 combined transition matrix
__device__ float g_G3[KTOT * NZ];          // G3[k=(d*32+c)][i] = (M^d B)[i][c]  (transposed for coalesced tap loads)
__device__ float g_Zeta[D_TAPS * NZ];      // Zeta[d][i] = (M^d z0)[i]
__device__ float g_BH[2][33 * NZ];         // ping-pong chain state, layout [c][j]

// ---------------------------------------------------------------------------
// Kernel 1: build M; init BH_0 = [B | z0], G3[k<32] = B^T, Zeta[0] = z0
// ---------------------------------------------------------------------------
__global__ __launch_bounds__(256) void k_build(
    const float* __restrict__ xn0, const float* __restrict__ xu0, const float* __restrict__ xo0,
    const float* __restrict__ Ann, const float* __restrict__ Kn,  const float* __restrict__ Cn,
    const float* __restrict__ Auu, const float* __restrict__ Ku,  const float* __restrict__ Cu,
    const float* __restrict__ Bpn, const float* __restrict__ Bpu,
    const float* __restrict__ Ao,  const float* __restrict__ Bo,  const float* __restrict__ Co)
{
    int q = blockIdx.x * 256 + threadIdx.x;   // 0 .. 262143
    int i = q >> 9, j = q & 511;
    float v;
    if (i < 128) {                                     // nat rows
        if (j < 128)       v = Ann[i * 128 + j] + Kn[i] * Cn[j];
        else if (j < 256)  v = Kn[i] * Cu[j - 128];
        else {
            int jp = j - 256; float s = 0.f;
            #pragma unroll 8
            for (int c = 0; c < 64; c++) s += Bpn[i * 64 + c] * Co[c * 256 + jp];
            v = s;
        }
    } else if (i < 256) {                              // unnat rows (x_nat dep cancels exactly)
        int ip = i - 128;
        if (j < 128)       v = 0.f;
        else if (j < 256)  { int jp = j - 128; v = Auu[ip * 128 + jp] + Ku[ip] * Cu[jp]; }
        else {
            int jp = j - 256; float s = 0.f;
            #pragma unroll 8
            for (int c = 0; c < 64; c++) s += Bpu[ip * 64 + c] * Co[c * 256 + jp];
            v = s;
        }
    } else {                                           // opsin rows
        int ip = i - 256;
        v = (j >= 256) ? Ao[ip * 256 + (j - 256)] : 0.f;
    }
    g_M[q] = v;

    if (q < 33 * NZ) {
        int jj = q & 511, cc = q >> 9;                 // cc in 0..32
        if (cc < 32) {
            float b = (jj >= 256) ? Bo[(jj - 256) * 32 + cc] : 0.f;
            g_BH[0][cc * NZ + jj] = b;
            g_G3[cc * NZ + jj]    = b;                 // k = 0*32 + cc
        } else {
            float z0j = (jj < 128) ? xn0[jj] : (jj < 256 ? xu0[jj - 128] : xo0[jj - 256]);
            g_BH[0][32 * NZ + jj] = z0j;
            g_Zeta[jj]            = z0j;               // Zeta[0] = z0
        }
    }
}

// ---------------------------------------------------------------------------
// Kernel 2: one chain step  BH_{d+1} = M * BH_d ; scatter into G3, Zeta
// grid: 66 x 256
// ---------------------------------------------------------------------------
__global__ __launch_bounds__(256) void k_chain(int d)
{
    int q = blockIdx.x * 256 + threadIdx.x;   // 0 .. 16895
    int i = q & 511, c = q >> 9;              // c in 0..32
    const float4* Mrow = (const float4*)(g_M + (size_t)i * NZ);
    const float4* srow = (const float4*)(g_BH[d & 1] + (size_t)c * NZ);
    float s = 0.f;
    #pragma unroll 8
    for (int k = 0; k < 128; k++) {
        float4 m = Mrow[k], x = srow[k];
        s += m.x * x.x + m.y * x.y + m.z * x.z + m.w * x.w;
    }
    g_BH[(d & 1) ^ 1][c * NZ + i] = s;
    if (c < 32) g_G3[(size_t)((d + 1) * 32 + c) * NZ + i] = s;
    else        g_Zeta[(d + 1) * NZ + i] = s;
}

// ---------------------------------------------------------------------------
// Kernel 3: FIR evaluation of all states, spill-free.
// block = 256 threads: tsub = (tid>>7)*16 picks t-half, ib = tid&127;
// each thread computes dims {ib, ib+128, ib+256, ib+384} for 16 timesteps.
// grid: 2049 blocks of 32 timesteps.
// ---------------------------------------------------------------------------
__global__ __launch_bounds__(256, 4) void k_fir(
    const float* __restrict__ U, float* __restrict__ out)
{
    const int tid  = threadIdx.x;
    const int t0   = blockIdx.x * 32;
    const int tsub = (tid >> 7) * 16;      // 0 or 16
    const int ib   = tid & 127;

    __shared__ float u_lds[44 * 32];       // rows r <-> u[t0 - 12 + r], rows 0..42 used

    for (int e = tid; e < 44 * 32; e += 256) {
        int row = e >> 5, c = e & 31;
        int gr = t0 - D_TAPS + row;
        u_lds[e] = (gr >= 0 && gr < T_STEPS) ? U[gr * 32 + c] : 0.f;
    }
    __syncthreads();

    float acc[4][16];
    #pragma unroll
    for (int q = 0; q < 4; q++)
        #pragma unroll
        for (int t = 0; t < 16; t++) acc[q][t] = 0.f;

    #pragma unroll 1
    for (int d = 0; d < D_TAPS; d++) {
        const int rbase = tsub + (D_TAPS - 1) - d;   // LDS row for tl=0
        #pragma unroll 1
        for (int cb = 0; cb < 8; cb++) {
            float h[4][4];
            #pragma unroll
            for (int j = 0; j < 4; j++) {
                const float* gp = g_G3 + (size_t)(d * 32 + cb * 4 + j) * NZ + ib;
                #pragma unroll
                for (int q = 0; q < 4; q++) h[q][j] = gp[q * 128];
            }
            #pragma unroll
            for (int tl = 0; tl < 16; tl++) {
                const float4 u4 = *(const float4*)&u_lds[(rbase + tl) * 32 + cb * 4];
                #pragma unroll
                for (int q = 0; q < 4; q++) {
                    acc[q][tl] = fmaf(h[q][0], u4.x, acc[q][tl]);
                    acc[q][tl] = fmaf(h[q][1], u4.y, acc[q][tl]);
                    acc[q][tl] = fmaf(h[q][2], u4.z, acc[q][tl]);
                    acc[q][tl] = fmaf(h[q][3], u4.w, acc[q][tl]);
                }
            }
        }
    }

    const size_t O1 = (size_t)T_STEPS;                    // x_nat_hist
    const size_t O2 = O1 + (size_t)(T_STEPS + 1) * 128;   // x_unnat_hist
    const size_t O3 = O2 + (size_t)(T_STEPS + 1) * 128;   // x_opsin_hist

    #pragma unroll 1
    for (int tl = 0; tl < 16; tl++) {
        int gt = t0 + tsub + tl;
        if (gt > T_STEPS) break;                          // uniform per wave
        float z0 = acc[0][tl], z1 = acc[1][tl], z2 = acc[2][tl], z3 = acc[3][tl];
        if (gt < D_TAPS) {                                // exact init-condition term
            z0 += g_Zeta[gt * NZ + ib];
            z1 += g_Zeta[gt * NZ + ib + 128];
            z2 += g_Zeta[gt * NZ + ib + 256];
            z3 += g_Zeta[gt * NZ + ib + 384];
        }
        out[O1 + (size_t)gt * 128 + ib]       = z0;
        out[O2 + (size_t)gt * 128 + ib]       = z1;
        out[O3 + (size_t)gt * 256 + ib]       = z2;
        out[O3 + (size_t)gt * 256 + 128 + ib] = z3;
    }
}

// ---------------------------------------------------------------------------
// Kernel 4: y_t = Cn . x_nat_hist[t] + Cu . x_unnat_hist[t], t in [0, T)
// 256 blocks x 256 threads; each wave handles 64 consecutive t.
// ---------------------------------------------------------------------------
__global__ __launch_bounds__(256) void k_y(
    const float* __restrict__ Cn, const float* __restrict__ Cu, float* __restrict__ out)
{
    const int lane = threadIdx.x & 63;
    const int w    = blockIdx.x * 4 + (threadIdx.x >> 6);
    const size_t O1 = (size_t)T_STEPS;
    const size_t O2 = O1 + (size_t)(T_STEPS + 1) * 128;

    const float4 c4 = (lane < 32) ? *(const float4*)(Cn + lane * 4)
                                  : *(const float4*)(Cu + (lane - 32) * 4);
    #pragma unroll 4
    for (int it = 0; it < 64; it++) {
        const int t = w * 64 + it;
        const float* xp = (lane < 32) ? (out + O1 + (size_t)t * 128 + lane * 4)
                                      : (out + O2 + (size_t)t * 128 + (lane - 32) * 4);
        float4 x4 = *(const float4*)xp;
        float yv = c4.x * x4.x + c4.y * x4.y + c4.z * x4.z + c4.w * x4.w;
        #pragma unroll
        for (int off = 32; off >= 1; off >>= 1) yv += __shfl_xor(yv, off, 64);
        if (lane == 0) out[t] = yv;
    }
}

extern "C" void kernel_launch(void* const* d_in, const int* in_sizes, int n_in,
                              void* d_out, int out_size, void* d_ws, size_t ws_size,
                              hipStream_t stream)
{
    const float* xn0 = (const float*)d_in[0];
    const float* xu0 = (const float*)d_in[1];
    const float* xo0 = (const float*)d_in[2];
    const float* U   = (const float*)d_in[3];
    const float* Ann = (const float*)d_in[4];
    const float* Kn  = (const float*)d_in[5];
    const float* Cn  = (const float*)d_in[6];
    const float* Auu = (const float*)d_in[7];
    const float* Ku  = (const float*)d_in[8];
    const float* Cu  = (const float*)d_in[9];
    const float* Bpn = (const float*)d_in[10];
    const float* Bpu = (const float*)d_in[11];
    const float* Ao  = (const float*)d_in[12];
    const float* Bo  = (const float*)d_in[13];
    const float* Co  = (const float*)d_in[14];
    float* out = (float*)d_out;

    k_build<<<dim3(1024), dim3(256), 0, stream>>>(xn0, xu0, xo0, Ann, Kn, Cn,
                                                  Auu, Ku, Cu, Bpn, Bpu, Ao, Bo, Co);
    for (int d = 0; d < D_TAPS - 1; d++)
        k_chain<<<dim3(66), dim3(256), 0, stream>>>(d);

    k_fir<<<dim3((T_STEPS + 1 + 31) / 32), dim3(256), 0, stream>>>(U, out);
    k_y<<<dim3(256), dim3(256), 0, stream>>>(Cn, Cu, out);
}

// Round 3
// 508.138 us; speedup vs baseline: 5.5642x; 1.5624x over previous
//
#include <hip/hip_runtime.h>

#define T_STEPS 65536
#define D_TAPS  12
#define NZ      512
#define KTOT    (D_TAPS * 32)   // 384
#define BT      64

typedef __attribute__((ext_vector_type(8))) short  short8;
typedef __attribute__((ext_vector_type(4))) float  floatx4;

// persistent device scratch (fully rewritten every call)
__device__ float g_M[NZ * NZ];             // 512x512 combined transition matrix
__device__ float g_Zeta[D_TAPS * NZ];      // Zeta[d][i] = (M^d z0)[i]  (fp32-exact init path)
__device__ float g_BH[2][33 * NZ];         // ping-pong chain state, layout [c][j]
__device__ short g_Gbf[NZ * KTOT];         // bf16 bits of (M^d B)[i][c], layout [i][k=d*32+c]

__device__ __forceinline__ short f2bf(float v) {   // RNE float->bf16 bits
    unsigned int b = __float_as_uint(v);
    unsigned int r = (b + 0x7FFFu + ((b >> 16) & 1u)) >> 16;
    return (short)r;
}

// ---------------------------------------------------------------------------
// Kernel 1: build M; init BH_0 = [B | z0], Gbf[:,k<32] = B, Zeta[0] = z0
// ---------------------------------------------------------------------------
__global__ __launch_bounds__(256) void k_build(
    const float* __restrict__ xn0, const float* __restrict__ xu0, const float* __restrict__ xo0,
    const float* __restrict__ Ann, const float* __restrict__ Kn,  const float* __restrict__ Cn,
    const float* __restrict__ Auu, const float* __restrict__ Ku,  const float* __restrict__ Cu,
    const float* __restrict__ Bpn, const float* __restrict__ Bpu,
    const float* __restrict__ Ao,  const float* __restrict__ Bo,  const float* __restrict__ Co)
{
    int q = blockIdx.x * 256 + threadIdx.x;   // 0 .. 262143
    int i = q >> 9, j = q & 511;
    float v;
    if (i < 128) {                                     // nat rows
        if (j < 128)       v = Ann[i * 128 + j] + Kn[i] * Cn[j];
        else if (j < 256)  v = Kn[i] * Cu[j - 128];
        else {
            int jp = j - 256; float s = 0.f;
            #pragma unroll 8
            for (int c = 0; c < 64; c++) s += Bpn[i * 64 + c] * Co[c * 256 + jp];
            v = s;
        }
    } else if (i < 256) {                              // unnat rows (x_nat dep cancels exactly)
        int ip = i - 128;
        if (j < 128)       v = 0.f;
        else if (j < 256)  { int jp = j - 128; v = Auu[ip * 128 + jp] + Ku[ip] * Cu[jp]; }
        else {
            int jp = j - 256; float s = 0.f;
            #pragma unroll 8
            for (int c = 0; c < 64; c++) s += Bpu[ip * 64 + c] * Co[c * 256 + jp];
            v = s;
        }
    } else {                                           // opsin rows
        int ip = i - 256;
        v = (j >= 256) ? Ao[ip * 256 + (j - 256)] : 0.f;
    }
    g_M[q] = v;

    if (q < 33 * NZ) {
        int jj = q & 511, cc = q >> 9;                 // cc in 0..32
        if (cc < 32) {
            float b = (jj >= 256) ? Bo[(jj - 256) * 32 + cc] : 0.f;
            g_BH[0][cc * NZ + jj]   = b;
            g_Gbf[jj * KTOT + cc]   = f2bf(b);         // d = 0
        } else {
            float z0j = (jj < 128) ? xn0[jj] : (jj < 256 ? xu0[jj - 128] : xo0[jj - 256]);
            g_BH[0][32 * NZ + jj] = z0j;
            g_Zeta[jj]            = z0j;               // Zeta[0] = z0
        }
    }
}

// ---------------------------------------------------------------------------
// Kernel 2: one chain step  BH_{d+1} = M * BH_d ; scatter into Gbf, Zeta
// grid: 66 x 256
// ---------------------------------------------------------------------------
__global__ __launch_bounds__(256) void k_chain(int d)
{
    int q = blockIdx.x * 256 + threadIdx.x;   // 0 .. 16895
    int i = q & 511, c = q >> 9;              // c in 0..32
    const float4* Mrow = (const float4*)(g_M + (size_t)i * NZ);
    const float4* srow = (const float4*)(g_BH[d & 1] + (size_t)c * NZ);
    float s = 0.f;
    #pragma unroll 8
    for (int k = 0; k < 128; k++) {
        float4 m = Mrow[k], x = srow[k];
        s += m.x * x.x + m.y * x.y + m.z * x.z + m.w * x.w;
    }
    g_BH[(d & 1) ^ 1][c * NZ + i] = s;
    if (c < 32) g_Gbf[(size_t)i * KTOT + (d + 1) * 32 + c] = f2bf(s);
    else        g_Zeta[(d + 1) * NZ + i] = s;
}

// ---------------------------------------------------------------------------
// Kernel 3: FIR as bf16 MFMA GEMM.  Z[t][i] = sum_k A[t][k] Gbf[k][i],
// A[t][d*32+c] = u[t-1-d][c] (Toeplitz view staged in LDS, zero-padded).
// block = 256 threads = 4 waves; wave w owns i-range [w*128, w*128+128).
// Each block covers BT=64 timesteps: 4 m-tiles x 8 n-tiles x 12 k-tiles.
// LDS u rows: stride 40 bf16 (80 B) -> b128 reads spread uniformly over banks.
// ---------------------------------------------------------------------------
__global__ __launch_bounds__(256, 2) void k_fir(
    const float* __restrict__ U, float* __restrict__ out)
{
    const int tid  = threadIdx.x;
    const int t0   = blockIdx.x * BT;
    const int w    = tid >> 6;
    const int lane = tid & 63;
    const int quad = lane >> 4;
    const int lq   = lane & 15;
    const int n0   = w * 128;

    __shared__ short u_sh[76 * 40];            // rows r <-> u[t0 - 12 + r], r in [0,74]

    for (int e = tid; e < 75 * 32; e += 256) {
        int row = e >> 5, c = e & 31;
        int gr = t0 - D_TAPS + row;
        float v = (gr >= 0 && gr < T_STEPS) ? U[gr * 32 + c] : 0.f;
        u_sh[row * 40 + c] = f2bf(v);
    }
    __syncthreads();

    floatx4 acc[4][8];
    #pragma unroll
    for (int mt = 0; mt < 4; mt++)
        #pragma unroll
        for (int nt = 0; nt < 8; nt++)
            acc[mt][nt] = (floatx4){0.f, 0.f, 0.f, 0.f};

    #pragma unroll 1
    for (int kt = 0; kt < D_TAPS; kt++) {      // k-tile == tap d (32-aligned)
        short8 a[4];
        #pragma unroll
        for (int mt = 0; mt < 4; mt++) {
            const int r = mt * 16 + lq + 11 - kt;    // row t-1-d in LDS coords
            a[mt] = *(const short8*)&u_sh[r * 40 + quad * 8];
        }
        #pragma unroll
        for (int nt = 0; nt < 8; nt++) {
            const short8 b = *(const short8*)(g_Gbf +
                (size_t)(n0 + nt * 16 + lq) * KTOT + kt * 32 + quad * 8);
            #pragma unroll
            for (int mt = 0; mt < 4; mt++)
                acc[mt][nt] = __builtin_amdgcn_mfma_f32_16x16x32_bf16(
                                  a[mt], b, acc[mt][nt], 0, 0, 0);
        }
    }

    const size_t O1 = (size_t)T_STEPS;                    // x_nat_hist
    const size_t O2 = O1 + (size_t)(T_STEPS + 1) * 128;   // x_unnat_hist
    const size_t O3 = O2 + (size_t)(T_STEPS + 1) * 128;   // x_opsin_hist

    #pragma unroll
    for (int mt = 0; mt < 4; mt++) {
        #pragma unroll
        for (int r = 0; r < 4; r++) {
            const int gt = t0 + mt * 16 + quad * 4 + r;   // D row = quad*4 + reg
            if (gt > T_STEPS) continue;
            #pragma unroll
            for (int nt = 0; nt < 8; nt++) {
                const int i = n0 + nt * 16 + lq;          // D col = lane&15
                float v = acc[mt][nt][r];
                if (gt < D_TAPS) v += g_Zeta[gt * NZ + i];  // exact M^t z0 term
                if (w == 0)      out[O1 + (size_t)gt * 128 + i]         = v;
                else if (w == 1) out[O2 + (size_t)gt * 128 + (i - 128)] = v;
                else             out[O3 + (size_t)gt * 256 + (i - 256)] = v;
            }
        }
    }
}

// ---------------------------------------------------------------------------
// Kernel 4: y_t = Cn . x_nat_hist[t] + Cu . x_unnat_hist[t], t in [0, T)
// ---------------------------------------------------------------------------
__global__ __launch_bounds__(256) void k_y(
    const float* __restrict__ Cn, const float* __restrict__ Cu, float* __restrict__ out)
{
    const int lane = threadIdx.x & 63;
    const int w    = blockIdx.x * 4 + (threadIdx.x >> 6);
    const size_t O1 = (size_t)T_STEPS;
    const size_t O2 = O1 + (size_t)(T_STEPS + 1) * 128;

    const float4 c4 = (lane < 32) ? *(const float4*)(Cn + lane * 4)
                                  : *(const float4*)(Cu + (lane - 32) * 4);
    #pragma unroll 4
    for (int it = 0; it < 64; it++) {
        const int t = w * 64 + it;
        const float* xp = (lane < 32) ? (out + O1 + (size_t)t * 128 + lane * 4)
                                      : (out + O2 + (size_t)t * 128 + (lane - 32) * 4);
        float4 x4 = *(const float4*)xp;
        float yv = c4.x * x4.x + c4.y * x4.y + c4.z * x4.z + c4.w * x4.w;
        #pragma unroll
        for (int off = 32; off >= 1; off >>= 1) yv += __shfl_xor(yv, off, 64);
        if (lane == 0) out[t] = yv;
    }
}

extern "C" void kernel_launch(void* const* d_in, const int* in_sizes, int n_in,
                              void* d_out, int out_size, void* d_ws, size_t ws_size,
                              hipStream_t stream)
{
    const float* xn0 = (const float*)d_in[0];
    const float* xu0 = (const float*)d_in[1];
    const float* xo0 = (const float*)d_in[2];
    const float* U   = (const float*)d_in[3];
    const float* Ann = (const float*)d_in[4];
    const float* Kn  = (const float*)d_in[5];
    const float* Cn  = (const float*)d_in[6];
    const float* Auu = (const float*)d_in[7];
    const float* Ku  = (const float*)d_in[8];
    const float* Cu  = (const float*)d_in[9];
    const float* Bpn = (const float*)d_in[10];
    const float* Bpu = (const float*)d_in[11];
    const float* Ao  = (const float*)d_in[12];
    const float* Bo  = (const float*)d_in[13];
    const float* Co  = (const float*)d_in[14];
    float* out = (float*)d_out;

    k_build<<<dim3(1024), dim3(256), 0, stream>>>(xn0, xu0, xo0, Ann, Kn, Cn,
                                                  Auu, Ku, Cu, Bpn, Bpu, Ao, Bo, Co);
    for (int d = 0; d < D_TAPS - 1; d++)
        k_chain<<<dim3(66), dim3(256), 0, stream>>>(d);

    k_fir<<<dim3((T_STEPS + 1 + BT - 1) / BT), dim3(256), 0, stream>>>(U, out);
    k_y<<<dim3(256), dim3(256), 0, stream>>>(Cn, Cu, out);
}

// Round 4
// 363.956 us; speedup vs baseline: 7.7685x; 1.3962x over previous
//
#include <hip/hip_runtime.h>

#define T_STEPS 65536
#define D_TAPS  8
#define NZ      512
#define KTOT    (D_TAPS * 32)   // 256
#define BT      32
#define NBLK    256
#define MTILES  ((T_STEPS + 1 + BT - 1) / BT)   // 2049

typedef __attribute__((ext_vector_type(8))) short  short8;
typedef __attribute__((ext_vector_type(4))) float  floatx4;

// persistent device scratch (fully rewritten every call)
__device__ float g_M[NZ * NZ];             // 512x512 combined transition matrix
__device__ float g_Zeta[D_TAPS * NZ];      // Zeta[d][i] = (M^d z0)[i]  (fp32-exact init path)
__device__ float g_BH[2][33 * NZ];         // ping-pong chain state, layout [c][j]
__device__ short g_Gbf[NZ * KTOT];         // bf16 bits of (M^d B)[i][c], layout [i][k=d*32+c]

__device__ __forceinline__ short f2bf(float v) {   // RNE float->bf16 bits
    unsigned int b = __float_as_uint(v);
    unsigned int r = (b + 0x7FFFu + ((b >> 16) & 1u)) >> 16;
    return (short)r;
}

// ---------------------------------------------------------------------------
// Kernel 1: build M; init BH_0 = [B | z0], Gbf[:,k<32] = B, Zeta[0] = z0
// ---------------------------------------------------------------------------
__global__ __launch_bounds__(256) void k_build(
    const float* __restrict__ xn0, const float* __restrict__ xu0, const float* __restrict__ xo0,
    const float* __restrict__ Ann, const float* __restrict__ Kn,  const float* __restrict__ Cn,
    const float* __restrict__ Auu, const float* __restrict__ Ku,  const float* __restrict__ Cu,
    const float* __restrict__ Bpn, const float* __restrict__ Bpu,
    const float* __restrict__ Ao,  const float* __restrict__ Bo,  const float* __restrict__ Co)
{
    int q = blockIdx.x * 256 + threadIdx.x;   // 0 .. 262143
    int i = q >> 9, j = q & 511;
    float v;
    if (i < 128) {                                     // nat rows
        if (j < 128)       v = Ann[i * 128 + j] + Kn[i] * Cn[j];
        else if (j < 256)  v = Kn[i] * Cu[j - 128];
        else {
            int jp = j - 256; float s = 0.f;
            #pragma unroll 8
            for (int c = 0; c < 64; c++) s += Bpn[i * 64 + c] * Co[c * 256 + jp];
            v = s;
        }
    } else if (i < 256) {                              // unnat rows (x_nat dep cancels exactly)
        int ip = i - 128;
        if (j < 128)       v = 0.f;
        else if (j < 256)  { int jp = j - 128; v = Auu[ip * 128 + jp] + Ku[ip] * Cu[jp]; }
        else {
            int jp = j - 256; float s = 0.f;
            #pragma unroll 8
            for (int c = 0; c < 64; c++) s += Bpu[ip * 64 + c] * Co[c * 256 + jp];
            v = s;
        }
    } else {                                           // opsin rows
        int ip = i - 256;
        v = (j >= 256) ? Ao[ip * 256 + (j - 256)] : 0.f;
    }
    g_M[q] = v;

    if (q < 33 * NZ) {
        int jj = q & 511, cc = q >> 9;                 // cc in 0..32
        if (cc < 32) {
            float b = (jj >= 256) ? Bo[(jj - 256) * 32 + cc] : 0.f;
            g_BH[0][cc * NZ + jj]   = b;
            g_Gbf[jj * KTOT + cc]   = f2bf(b);         // d = 0
        } else {
            float z0j = (jj < 128) ? xn0[jj] : (jj < 256 ? xu0[jj - 128] : xo0[jj - 256]);
            g_BH[0][32 * NZ + jj] = z0j;
            g_Zeta[jj]            = z0j;               // Zeta[0] = z0
        }
    }
}

// ---------------------------------------------------------------------------
// Kernel 2: one chain step  BH_{d+1} = M * BH_d ; scatter into Gbf, Zeta
// ---------------------------------------------------------------------------
__global__ __launch_bounds__(256) void k_chain(int d)
{
    int q = blockIdx.x * 256 + threadIdx.x;   // 0 .. 16895
    int i = q & 511, c = q >> 9;              // c in 0..32
    const float4* Mrow = (const float4*)(g_M + (size_t)i * NZ);
    const float4* srow = (const float4*)(g_BH[d & 1] + (size_t)c * NZ);
    float s = 0.f;
    #pragma unroll 8
    for (int k = 0; k < 128; k++) {
        float4 m = Mrow[k], x = srow[k];
        s += m.x * x.x + m.y * x.y + m.z * x.z + m.w * x.w;
    }
    g_BH[(d & 1) ^ 1][c * NZ + i] = s;
    if (c < 32) g_Gbf[(size_t)i * KTOT + (d + 1) * 32 + c] = f2bf(s);
    else        g_Zeta[(d + 1) * NZ + i] = s;
}

// ---------------------------------------------------------------------------
// Kernel 3: persistent-block FIR GEMM + fused y.
// 256 blocks x 512 threads (8 waves). Wave w owns n-cols [w*64, w*64+64).
// B fragments (8 kt x 4 nt, bf16) loaded ONCE into registers, then the block
// grid-strides over 2049 m-tiles of BT=32 timesteps. Steady state touches
// only LDS (u tile) + MFMA + nontemporal stores: no global loads to hide.
// ---------------------------------------------------------------------------
__global__ __launch_bounds__(512) void k_fir(
    const float* __restrict__ U, const float* __restrict__ Cn, const float* __restrict__ Cu,
    float* __restrict__ out)
{
    const int tid  = threadIdx.x;
    const int w    = tid >> 6;          // wave 0..7
    const int lane = tid & 63;
    const int quad = lane >> 4;
    const int lq   = lane & 15;
    const int col0 = w * 64;            // this wave's first n-col

    __shared__ short u_sh[40 * 40];     // rows r <-> u[t0 - 8 + r], r in [0,39]
    __shared__ float ypart[4][BT];

    // ---- one-time: B fragments into registers (128 VGPRs) ----
    short8 bfr[D_TAPS][4];
    #pragma unroll
    for (int kt = 0; kt < D_TAPS; kt++)
        #pragma unroll
        for (int nt = 0; nt < 4; nt++)
            bfr[kt][nt] = *(const short8*)(g_Gbf +
                (size_t)(col0 + nt * 16 + lq) * KTOT + kt * 32 + quad * 8);

    float cyv[4];
    #pragma unroll
    for (int nt = 0; nt < 4; nt++) {
        int i = col0 + nt * 16 + lq;
        cyv[nt] = (w < 2) ? Cn[i] : (w < 4 ? Cu[i - 128] : 0.f);
    }

    // output region base/stride per wave (uniform)
    const size_t O1 = (size_t)T_STEPS;
    const size_t O2 = O1 + (size_t)(T_STEPS + 1) * 128;
    const size_t O3 = O2 + (size_t)(T_STEPS + 1) * 128;
    float* obase; int ostr, cbase;
    if      (w < 2) { obase = out + O1; ostr = 128; cbase = col0; }
    else if (w < 4) { obase = out + O2; ostr = 128; cbase = col0 - 128; }
    else            { obase = out + O3; ostr = 256; cbase = col0 - 256; }

    #pragma unroll 1
    for (int tb = blockIdx.x; tb < MTILES; tb += NBLK) {
        const int t0 = tb * BT;

        // stage u rows [t0-8, t0+31], zero-padded, bf16, stride 40
        #pragma unroll 1
        for (int e = tid; e < 40 * 32; e += 512) {
            int row = e >> 5, c = e & 31;
            int gr = t0 - D_TAPS + row;
            float v = (gr >= 0 && gr < T_STEPS) ? U[gr * 32 + c] : 0.f;
            u_sh[row * 40 + c] = f2bf(v);
        }
        __syncthreads();

        floatx4 acc[2][4];
        #pragma unroll
        for (int mt = 0; mt < 2; mt++)
            #pragma unroll
            for (int nt = 0; nt < 4; nt++)
                acc[mt][nt] = (floatx4){0.f, 0.f, 0.f, 0.f};

        #pragma unroll
        for (int kt = 0; kt < D_TAPS; kt++) {
            short8 a[2];
            #pragma unroll
            for (int mt = 0; mt < 2; mt++) {
                const int r = mt * 16 + lq + (D_TAPS - 1) - kt;   // u[t-1-d]
                a[mt] = *(const short8*)&u_sh[r * 40 + quad * 8];
            }
            #pragma unroll
            for (int nt = 0; nt < 4; nt++)
                #pragma unroll
                for (int mt = 0; mt < 2; mt++)
                    acc[mt][nt] = __builtin_amdgcn_mfma_f32_16x16x32_bf16(
                                      a[mt], bfr[kt][nt], acc[mt][nt], 0, 0, 0);
        }

        // epilogue: store z (nontemporal), fold y partials for waves 0..3
        #pragma unroll
        for (int mt = 0; mt < 2; mt++) {
            #pragma unroll
            for (int r = 0; r < 4; r++) {
                const int lrow = mt * 16 + quad * 4 + r;
                const int gt = t0 + lrow;
                const bool valid = (gt <= T_STEPS);
                float p = 0.f;
                #pragma unroll
                for (int nt = 0; nt < 4; nt++) {
                    float v = acc[mt][nt][r];
                    if (gt < D_TAPS) v += g_Zeta[gt * NZ + col0 + nt * 16 + lq];
                    if (valid)
                        __builtin_nontemporal_store(v,
                            obase + (size_t)gt * ostr + cbase + nt * 16 + lq);
                    p = fmaf(cyv[nt], v, p);
                }
                if (w < 4) {
                    p += __shfl_xor(p, 1, 64);
                    p += __shfl_xor(p, 2, 64);
                    p += __shfl_xor(p, 4, 64);
                    p += __shfl_xor(p, 8, 64);
                    if (lq == 0) ypart[w][lrow] = p;
                }
            }
        }
        __syncthreads();
        if (tid < BT) {
            const int gt = t0 + tid;
            if (gt < T_STEPS) {
                float y = ypart[0][tid] + ypart[1][tid] + ypart[2][tid] + ypart[3][tid];
                __builtin_nontemporal_store(y, out + gt);
            }
        }
        // next iteration's staging is separated from this epilogue by the
        // post-stage __syncthreads (u_sh reads all completed before it).
    }
}

extern "C" void kernel_launch(void* const* d_in, const int* in_sizes, int n_in,
                              void* d_out, int out_size, void* d_ws, size_t ws_size,
                              hipStream_t stream)
{
    const float* xn0 = (const float*)d_in[0];
    const float* xu0 = (const float*)d_in[1];
    const float* xo0 = (const float*)d_in[2];
    const float* U   = (const float*)d_in[3];
    const float* Ann = (const float*)d_in[4];
    const float* Kn  = (const float*)d_in[5];
    const float* Cn  = (const float*)d_in[6];
    const float* Auu = (const float*)d_in[7];
    const float* Ku  = (const float*)d_in[8];
    const float* Cu  = (const float*)d_in[9];
    const float* Bpn = (const float*)d_in[10];
    const float* Bpu = (const float*)d_in[11];
    const float* Ao  = (const float*)d_in[12];
    const float* Bo  = (const float*)d_in[13];
    const float* Co  = (const float*)d_in[14];
    float* out = (float*)d_out;

    k_build<<<dim3(1024), dim3(256), 0, stream>>>(xn0, xu0, xo0, Ann, Kn, Cn,
                                                  Auu, Ku, Cu, Bpn, Bpu, Ao, Bo, Co);
    for (int d = 0; d < D_TAPS - 1; d++)
        k_chain<<<dim3(66), dim3(256), 0, stream>>>(d);

    k_fir<<<dim3(NBLK), dim3(512), 0, stream>>>(U, Cn, Cu, out);
}